// Round 3
// baseline (650.328 us; speedup 1.0000x reference)
//
#include <hip/hip_runtime.h>

typedef float f4 __attribute__((ext_vector_type(4)));
typedef int   i4 __attribute__((ext_vector_type(4)));

static constexpr int D = 128;
// LDS-staged tables: atom(46), deg(6), chg(11), h(5), chi(4) = 72 rows = 36 KiB.
// E_bond / E_hyb / W / b live in registers (histogram + select tree).
static constexpr int NR_ATOM = 46, NR_DEG = 6, NR_CHG = 11, NR_H = 5, NR_CHI = 4;
static constexpr int OFF_ATOM = 0;
static constexpr int OFF_DEG  = OFF_ATOM + NR_ATOM * D;   // 5888
static constexpr int OFF_CHG  = OFF_DEG  + NR_DEG  * D;   // 6656
static constexpr int OFF_H    = OFF_CHG  + NR_CHG  * D;   // 8064
static constexpr int OFF_CHI  = OFF_H    + NR_H    * D;   // 8704
static constexpr int LDS_FLOATS = OFF_CHI + NR_CHI * D;   // 9216 = 36 KiB

struct Idx {
    int ia, ide, ic, ih, inh, ix;
    i4 bc;
    float s0, s1, s2;
};

__device__ __forceinline__ Idx load_idx(const int* __restrict__ atom_idx,
                                        const int* __restrict__ degree_idx,
                                        const int* __restrict__ charge_idx,
                                        const int* __restrict__ hybrid_idx,
                                        const int* __restrict__ numh_idx,
                                        const int* __restrict__ chiral_idx,
                                        const int* __restrict__ bond_counts,
                                        const float* __restrict__ scalar3,
                                        int n) {
    Idx r;
    r.ia  = atom_idx[n];
    r.ide = degree_idx[n];
    r.ic  = charge_idx[n];
    r.ih  = hybrid_idx[n];
    r.inh = numh_idx[n];
    r.ix  = chiral_idx[n];
    r.bc  = *(const i4*)(bond_counts + 4 * (size_t)n);
    r.s0  = scalar3[3 * (size_t)n + 0];
    r.s1  = scalar3[3 * (size_t)n + 1];
    r.s2  = scalar3[3 * (size_t)n + 2];
    return r;
}

__global__ __launch_bounds__(512, 4)
void atom_featurizer_kernel(const int*   __restrict__ atom_idx,
                            const int*   __restrict__ degree_idx,
                            const int*   __restrict__ charge_idx,
                            const int*   __restrict__ hybrid_idx,
                            const int*   __restrict__ numh_idx,
                            const int*   __restrict__ chiral_idx,
                            const int*   __restrict__ bond_counts,  // [N,4]
                            const float* __restrict__ scalar3,      // [N,3]
                            const float* __restrict__ E_atom,
                            const float* __restrict__ E_deg,
                            const float* __restrict__ E_chg,
                            const float* __restrict__ E_hyb,
                            const float* __restrict__ E_h,
                            const float* __restrict__ E_chi,
                            const float* __restrict__ E_bond,
                            const float* __restrict__ W,            // [7,D]
                            const float* __restrict__ b,            // [D]
                            float*       __restrict__ out,          // [N,D]
                            int N)
{
    __shared__ float lds[LDS_FLOATS];
    const int tid = threadIdx.x;

    // ---- stage the 5 gather tables into LDS (36 KiB, float4) ----
    {
        const float* srcs[5] = {E_atom, E_deg, E_chg, E_h, E_chi};
        const int    offs[5] = {OFF_ATOM, OFF_DEG, OFF_CHG, OFF_H, OFF_CHI};
        const int    cnts[5] = {NR_ATOM*D, NR_DEG*D, NR_CHG*D, NR_H*D, NR_CHI*D};
        for (int t = 0; t < 5; ++t) {
            const f4* s = (const f4*)srcs[t];
            f4* d = (f4*)(lds + offs[t]);
            const int n4 = cnts[t] >> 2;
            for (int i = tid; i < n4; i += 512) d[i] = s[i];
        }
    }

    const int lane = tid & 31;          // 32 lanes per atom, 16 B each
    const int grp  = tid >> 5;
    const int d0   = lane << 2;         // float offset within the 128-float row
    const int stride = (int)gridDim.x * 16;

    // ---- loop-invariant registers (from global; tables are L2-hot) ----
    auto ldg = [&](const float* p, int row) -> f4 {
        return *(const f4*)(p + row * D + d0);
    };
    const f4 w0 = ldg(W,0), w1 = ldg(W,1), w2 = ldg(W,2), w3 = ldg(W,3),
             w4 = ldg(W,4), w5 = ldg(W,5), w6 = ldg(W,6);
    const f4 bias = *(const f4*)(b + d0);
    const f4 eb1 = ldg(E_bond,1), eb2 = ldg(E_bond,2),
             eb3 = ldg(E_bond,3), eb4 = ldg(E_bond,4);
    const f4 hy0 = ldg(E_hyb,0), hy1 = ldg(E_hyb,1), hy2 = ldg(E_hyb,2);

    __syncthreads();

    auto ldl = [&](int off) -> f4 { return *(const f4*)(lds + off + d0); };

    int n = (int)blockIdx.x * 16 + grp;
    if (n >= N) return;

    Idx cur = load_idx(atom_idx, degree_idx, charge_idx, hybrid_idx, numh_idx,
                       chiral_idx, bond_counts, scalar3, n);

    while (true) {
        const int nn = n + stride;
        const bool more = nn < N;
        // software-pipeline: issue next iteration's index loads before compute
        Idx nxt = load_idx(atom_idx, degree_idx, charge_idx, hybrid_idx,
                           numh_idx, chiral_idx, bond_counts, scalar3,
                           more ? nn : n);

        const i4 bc = cur.bc;

        // two accumulator chains for ILP
        f4 a0 = ldl(OFF_ATOM + cur.ia  * D);
        f4 a1 = ldl(OFF_DEG  + cur.ide * D);
        a0 += ldl(OFF_CHG + cur.ic  * D);
        a1 += ldl(OFF_H   + cur.inh * D);
        a0 += ldl(OFF_CHI + cur.ix  * D);

        // hybrid from registers (3-row select tree)
        a1 += (cur.ih == 0) ? hy0 : ((cur.ih == 1) ? hy1 : hy2);

        // bond context via histogram: sum_j [bc_j>0]*E_bond[bc_j]
        //                           = sum_{v=1..4} c_v * E_bond[v]
        const int c1 = (bc.x==1)+(bc.y==1)+(bc.z==1)+(bc.w==1);
        const int c2 = (bc.x==2)+(bc.y==2)+(bc.z==2)+(bc.w==2);
        const int c3 = (bc.x==3)+(bc.y==3)+(bc.z==3)+(bc.w==3);
        const int c4 = (bc.x==4)+(bc.y==4)+(bc.z==4)+(bc.w==4);
        a0 += (float)c1 * eb1;
        a1 += (float)c2 * eb2;
        a0 += (float)c3 * eb3;
        a1 += (float)c4 * eb4;

        // scal @ W + b,  scal = [s0,s1,s2, bc/4]
        a0 += cur.s0 * w0;
        a1 += cur.s1 * w1;
        a0 += cur.s2 * w2;
        const float t0 = (float)bc.x * 0.25f;
        const float t1 = (float)bc.y * 0.25f;
        const float t2 = (float)bc.z * 0.25f;
        const float t3 = (float)bc.w * 0.25f;
        a0 += t0 * w3;
        a1 += t1 * w4;
        a0 += t2 * w5;
        a1 += t3 * w6;
        a0 += bias;

        const f4 r = a0 + a1;
        __builtin_nontemporal_store(r, (f4*)(out + (size_t)n * D + d0));

        if (!more) break;
        cur = nxt;
        n = nn;
    }
}

extern "C" void kernel_launch(void* const* d_in, const int* in_sizes, int n_in,
                              void* d_out, int out_size, void* d_ws, size_t ws_size,
                              hipStream_t stream) {
    const int*   atom_idx    = (const int*)d_in[0];
    const int*   degree_idx  = (const int*)d_in[1];
    const int*   charge_idx  = (const int*)d_in[2];
    const int*   hybrid_idx  = (const int*)d_in[3];
    const int*   numh_idx    = (const int*)d_in[4];
    const int*   chiral_idx  = (const int*)d_in[5];
    const int*   bond_counts = (const int*)d_in[6];
    const float* scalar3     = (const float*)d_in[7];
    const float* E_atom      = (const float*)d_in[8];
    const float* E_deg       = (const float*)d_in[9];
    const float* E_chg       = (const float*)d_in[10];
    const float* E_hyb       = (const float*)d_in[11];
    const float* E_h         = (const float*)d_in[12];
    const float* E_chi       = (const float*)d_in[13];
    const float* E_bond      = (const float*)d_in[14];
    const float* W           = (const float*)d_in[15];
    const float* b           = (const float*)d_in[16];
    float*       out         = (float*)d_out;
    const int N = in_sizes[0];

    // 512 blocks = 2 blocks/CU guaranteed resident (VGPR-capped at 4 waves/EU),
    // balanced grid-stride over atoms; 16 atom-groups per block.
    atom_featurizer_kernel<<<512, 512, 0, stream>>>(
        atom_idx, degree_idx, charge_idx, hybrid_idx, numh_idx, chiral_idx,
        bond_counts, scalar3, E_atom, E_deg, E_chg, E_hyb, E_h, E_chi, E_bond,
        W, b, out, N);
}